// Round 6
// baseline (205.535 us; speedup 1.0000x reference)
//
#include <hip/hip_runtime.h>
#include <math.h>

#pragma clang fp contract(off)

#define BN 4
#define SX 512
#define SY 512
#define NPIX (BN * SX * SY)
#define MU 5
#define MB (1024 * 1024)
#define NBLOCKS 2048   // 8 slabs x 256 rows

struct DogW  { float g[7];  float tw; };
struct FdogW { float g[10]; float tw; };

// tanh via expm1 identity: tanh(d) = expm1(2|d|) / (expm1(2|d|) + 2), odd.
__device__ __forceinline__ float fast_tanh_f32(float dF) {
    double d = (double)dF;
    double y = fabs(d);
    double t = expm1(2.0 * y);
    double r = t / (t + 2.0);
    if (y > 350.0) r = 1.0;
    return (float)copysign(r, d);
}

__device__ __forceinline__ float img_at(const float* __restrict__ img, int b, int x, int y) {
    if (x < 0 || x >= SX || y < 0 || y >= SY) return 0.0f;
    return img[(size_t)b * SX * SY + (size_t)x * SY + y];
}

// Slab mapping: grid (8, 256), 256 thr, 2 px/thread.
// blockIdx.x = slab = b*2 + rowHalf  ->  linear_id % 8 == slab  ->  stable XCD
// blockIdx.y = row within the 256-row half. Every kernel uses this mapping so
// the XCD that writes a slab is the XCD that reads it in the next stage.
#define SLAB_DECODE                                   \
    int slab = blockIdx.x;                            \
    int b    = slab >> 1;                             \
    int xi   = ((slab & 1) << 8) + blockIdx.y;        \
    size_t base = (size_t)b * SX * SY;                \
    size_t rowb = base + (size_t)xi * SY;

// Stage 1: Sobel -> mag, tangent, per-block max (no atomics).
__global__ __launch_bounds__(256) void k_sobel(const float* __restrict__ img,
                                               float* __restrict__ mag,
                                               float2* __restrict__ tang,
                                               float* __restrict__ partial) {
#pragma clang fp contract(off)
    SLAB_DECODE
    float bmax = 0.0f;
#pragma unroll
    for (int half = 0; half < 2; ++half) {
        int yi = (int)threadIdx.x + half * 256;

        float v00 = img_at(img, b, xi - 1, yi - 1);
        float v01 = img_at(img, b, xi - 1, yi    );
        float v02 = img_at(img, b, xi - 1, yi + 1);
        float v10 = img_at(img, b, xi,     yi - 1);
        float v12 = img_at(img, b, xi,     yi + 1);
        float v20 = img_at(img, b, xi + 1, yi - 1);
        float v21 = img_at(img, b, xi + 1, yi    );
        float v22 = img_at(img, b, xi + 1, yi + 1);

        float s0 = (-1.0f * v00);
        s0 = s0 + (-2.0f * v01);
        s0 = s0 + (-1.0f * v02);
        s0 = s0 + ( 1.0f * v20);
        s0 = s0 + ( 2.0f * v21);
        s0 = s0 + ( 1.0f * v22);
        float s1 = (-1.0f * v00);
        s1 = s1 + ( 1.0f * v02);
        s1 = s1 + (-2.0f * v10);
        s1 = s1 + ( 2.0f * v12);
        s1 = s1 + (-1.0f * v20);
        s1 = s1 + ( 1.0f * v22);

        float m = sqrtf((s0 * s0) + (s1 * s1));
        mag[rowb + yi] = m;

        float tx = -s1, ty = s0;
        float n = sqrtf((tx * tx) + (ty * ty));
        float d = (n == 0.0f) ? 1.0f : n;
        tang[rowb + yi] = make_float2(tx / d, ty / d);
        bmax = fmaxf(bmax, m);
    }

    for (int off = 32; off > 0; off >>= 1) bmax = fmaxf(bmax, __shfl_down(bmax, off, 64));
    __shared__ float red[4];
    int lane = threadIdx.x & 63;
    int wid  = threadIdx.x >> 6;
    if (lane == 0) red[wid] = bmax;
    __syncthreads();
    if (threadIdx.x == 0) {
        float bm = fmaxf(fmaxf(red[0], red[1]), fmaxf(red[2], red[3]));
        partial[blockIdx.x + 8 * blockIdx.y] = bm;
    }
}

// Stage 2: reduce per-block partials -> global max bits (one block).
__global__ void k_reduce(const float* __restrict__ partial, unsigned int* __restrict__ maxbits) {
    float m = 0.0f;
    for (int i = threadIdx.x; i < NBLOCKS; i += 256) m = fmaxf(m, partial[i]);
    for (int off = 32; off > 0; off >>= 1) m = fmaxf(m, __shfl_down(m, off, 64));
    __shared__ float red[4];
    int lane = threadIdx.x & 63;
    int wid  = threadIdx.x >> 6;
    if (lane == 0) red[wid] = m;
    __syncthreads();
    if (threadIdx.x == 0) {
        float bm = fmaxf(fmaxf(red[0], red[1]), fmaxf(red[2], red[3]));
        *maxbits = __float_as_uint(bm);
    }
}

// Stage 2b (fallback only): mag /= max(mag)
__global__ void k_norm(float* __restrict__ mag, const unsigned int* __restrict__ maxbits) {
    int i = blockIdx.x * blockDim.x + threadIdx.x;
    float mx = __uint_as_float(*maxbits);
    mag[i] = mag[i] / mx;
}

// Precompute tanh difference fields; normalization fused (single-rounded div).
__global__ __launch_bounds__(256) void k_tanh(const float* __restrict__ mag,
                                              const unsigned int* __restrict__ maxbits,
                                              float* __restrict__ TV, float* __restrict__ TH) {
#pragma clang fp contract(off)
    SLAB_DECODE
    float mx = __uint_as_float(*maxbits);
#pragma unroll
    for (int half = 0; half < 2; ++half) {
        int yi = (int)threadIdx.x + half * 256;
        size_t idx = rowb + yi;
        float cm = mag[idx] / mx;
#pragma unroll
        for (int k = 1; k <= 5; ++k) {
            if (xi + k < SX) {
                float nm = mag[idx + (size_t)k * SY] / mx;
                TV[(size_t)(k - 1) * NPIX + idx] = fast_tanh_f32(nm - cm);
            }
        }
#pragma unroll
        for (int k = 1; k <= 5; ++k) {
            if (yi + k < SY) {
                float nm = mag[idx + k] / mx;
                TH[(size_t)(k - 1) * NPIX + idx] = fast_tanh_f32(nm - cm);
            }
        }
    }
}

// Stage 3a: V-pass. Plain per-pixel loads; slab mapping keeps the ±5-row taps
// and TV planes in the local XCD's L2. Bit-exact reference arithmetic.
__global__ __launch_bounds__(256) void k_etf_v(const float2* __restrict__ tsrc,
                                               float2* __restrict__ tdst,
                                               const float* __restrict__ TV) {
#pragma clang fp contract(off)
    SLAB_DECODE
#pragma unroll
    for (int half = 0; half < 2; ++half) {
        int yi = (int)threadIdx.x + half * 256;
        size_t idx = rowb + yi;
        float2 ct = tsrc[idx];

        float sx = 0.0f, sy = 0.0f;
#pragma unroll
        for (int k = -MU; k <= MU; ++k) {
            int nx = xi + k;
            if (nx < 0 || nx >= SX) continue;
            size_t nidx = idx + (size_t)k * SY;
            float2 nt = tsrc[nidx];
            float th;
            if (k > 0)      th =  TV[(size_t)(k - 1) * NPIX + idx];
            else if (k < 0) th = -TV[(size_t)(-k - 1) * NPIX + nidx];
            else            th =  0.0f;
            float dot = (ct.x * nt.x) + (ct.y * nt.y);
            float w   = ((th + 1.0f) * dot) * 0.5f;
            sx = sx + (nt.x * w);
            sy = sy + (nt.y * w);
        }
        float n = sqrtf((sx * sx) + (sy * sy));
        float d = (n == 0.0f) ? 1.0f : n;
        tdst[idx] = make_float2(sx / d, sy / d);
    }
}

// Stage 3b: H-pass. Row staged in LDS; slab mapping keeps producer XCD-local.
__global__ __launch_bounds__(256) void k_etf_h(const float2* __restrict__ tsrc,
                                               float2* __restrict__ tdst,
                                               const float* __restrict__ TH) {
#pragma clang fp contract(off)
    SLAB_DECODE
    int tid = threadIdx.x;

    __shared__ __align__(16) float2 sT[SY];        // 4 KB
    __shared__ __align__(16) float  sTH[5][SY];    // 10 KB

    ((float4*)sT)[tid] = ((const float4*)(tsrc + rowb))[tid];
    for (int i = tid; i < 5 * (SY / 4); i += 256) {
        int j = i >> 7;
        int c = i & 127;
        ((float4*)&sTH[0][0])[i] = ((const float4*)(TH + (size_t)j * NPIX + rowb))[c];
    }
    __syncthreads();

#pragma unroll
    for (int half = 0; half < 2; ++half) {
        int yi = tid + half * 256;
        float2 ct = sT[yi];
        float sx = 0.0f, sy = 0.0f;
#pragma unroll
        for (int k = -MU; k <= MU; ++k) {
            int ny = yi + k;
            if (ny < 0 || ny >= SY) continue;
            float2 nt = sT[ny];
            float th;
            if (k > 0)      th =  sTH[k - 1][yi];
            else if (k < 0) th = -sTH[-k - 1][ny];
            else            th =  0.0f;
            float dot = (ct.x * nt.x) + (ct.y * nt.y);
            float w   = ((th + 1.0f) * dot) * 0.5f;
            sx = sx + (nt.x * w);
            sy = sy + (nt.y * w);
        }
        float n = sqrtf((sx * sx) + (sy * sy));
        float d = (n == 0.0f) ? 1.0f : n;
        tdst[rowb + yi] = make_float2(sx / d, sy / d);
    }
}

// Stage 3 (fallback, inline ocml tanh) — only if workspace is too small.
__global__ void k_etf(const float2* __restrict__ tsrc, float2* __restrict__ tdst,
                      const float* __restrict__ mag, int vert) {
#pragma clang fp contract(off)
    int yi = blockIdx.x * blockDim.x + threadIdx.x;
    int xi = blockIdx.y;
    int b  = blockIdx.z;
    size_t base = (size_t)b * SX * SY;
    size_t idx  = base + (size_t)xi * SY + yi;

    float  cm = mag[idx];
    float2 ct = tsrc[idx];

    float sx = 0.0f, sy = 0.0f;
    for (int k = -MU; k <= MU; ++k) {
        int nx = xi + (vert ? k : 0);
        int ny = yi + (vert ? 0 : k);
        if (nx < 0 || nx >= SX || ny < 0 || ny >= SY) continue;
        size_t nidx = base + (size_t)nx * SY + ny;
        float  nm = mag[nidx];
        float2 nt = tsrc[nidx];
        float dot = (ct.x * nt.x) + (ct.y * nt.y);
        float th  = (float)tanh((double)(nm - cm));
        float w   = ((th + 1.0f) * dot) * 0.5f;
        sx = sx + (nt.x * w);
        sy = sy + (nt.y * w);
    }
    float n = sqrtf((sx * sx) + (sy * sy));
    float d = (n == 0.0f) ? 1.0f : n;
    tdst[idx] = make_float2(sx / d, sy / d);
}

// Stage 4: DoG along the perpendicular (gathers stay within ±3 rows -> slab-local).
__global__ __launch_bounds__(256) void k_dog(const float* __restrict__ img,
                                             const float2* __restrict__ etf,
                                             float* __restrict__ dog, DogW w) {
#pragma clang fp contract(off)
    SLAB_DECODE
#pragma unroll
    for (int half = 0; half < 2; ++half) {
        int yi = (int)threadIdx.x + half * 256;
        size_t idx = rowb + yi;

        float2 e = etf[idx];
        float perx = -e.y;
        float pery =  e.x;
        float xf = (float)xi, yf = (float)yi;

        float acc = 0.0f;
#pragma unroll
        for (int t = -3; t <= 3; ++t) {
            float tf  = (float)t;
            float ptx = xf + (perx * tf);
            float pty = yf + (pery * tf);
            int px = (int)rintf(fminf(fmaxf(ptx, 0.0f), (float)(SX - 1)));
            int py = (int)rintf(fminf(fmaxf(pty, 0.0f), (float)(SY - 1)));
            float il = img[base + (size_t)px * SY + py];
            acc = acc + (il * w.g[t + 3]);
        }
        dog[idx] = acc / w.tw;
    }
}

// Stage 5: FDoG. Dual-chain ILP walk (drift <= 9 px -> slab-local reads).
__global__ __launch_bounds__(256) void k_fdog(const float* __restrict__ dog,
                                              const float2* __restrict__ etf,
                                              int* __restrict__ out, FdogW w) {
#pragma clang fp contract(off)
    SLAB_DECODE
    for (int half = 0; half < 2; ++half) {
        int yi = (int)threadIdx.x + half * 256;
        size_t idx = rowb + yi;

        float d1[9];
        float d2[10];
        float2 e0 = etf[idx];
        float2 e1 = e0, e2 = e0;
        int p1x = xi, p1y = yi;
        int p2x = xi, p2y = yi;
        d2[0] = dog[idx];

#pragma unroll
        for (int s = 1; s <= 9; ++s) {
            float fx1 = (float)p1x + (e1.x * -1.0f);
            float fy1 = (float)p1y + (e1.y * -1.0f);
            p1x = (int)rintf(fminf(fmaxf(fx1, 0.0f), (float)(SX - 1)));
            p1y = (int)rintf(fminf(fmaxf(fy1, 0.0f), (float)(SY - 1)));
            size_t i1 = base + (size_t)p1x * SY + p1y;
            float fx2 = (float)p2x + (e2.x * 1.0f);
            float fy2 = (float)p2y + (e2.y * 1.0f);
            p2x = (int)rintf(fminf(fmaxf(fx2, 0.0f), (float)(SX - 1)));
            p2y = (int)rintf(fminf(fmaxf(fy2, 0.0f), (float)(SY - 1)));
            size_t i2 = base + (size_t)p2x * SY + p2y;

            d1[s - 1] = dog[i1];
            d2[s]     = dog[i2];
            if (s < 9) {
                e1 = etf[i1];
                e2 = etf[i2];
            }
        }

        float acc = 0.0f;
#pragma unroll
        for (int s = 1; s <= 9; ++s) acc = acc + (d1[s - 1] * w.g[s]);
        acc = acc + (d2[0] * w.g[0]);
#pragma unroll
        for (int s = 1; s <= 9; ++s) acc = acc + (d2[s] * w.g[s]);

        float fv = acc / w.tw;
        float th = 1.0f + fast_tanh_f32(fv);
        out[idx] = ((fv < 0.0f) && (th < 0.7f)) ? 0 : 1;
    }
}

static double gpdf(double v, double sig) {
    return exp(-(v * v) / (2.0 * sig * sig)) / (sqrt(2.0 * M_PI) * sig);
}

extern "C" void kernel_launch(void* const* d_in, const int* in_sizes, int n_in,
                              void* d_out, int out_size, void* d_ws, size_t ws_size,
                              hipStream_t stream) {
    const float* img = (const float*)d_in[0];
    int* out = (int*)d_out;
    char* ws = (char*)d_ws;

    // Workspace layout (60 MB + 8 KB + 4 B):
    //   mag [0,4MB) | tA [4,12) | tB [12,20) (dog aliases) | TV [20,40) | TH [40,60)
    //   partial [60MB, +8KB) | maxbits [+4)
    const size_t need = (size_t)60 * MB + NBLOCKS * sizeof(float) + 4;
    bool fast = ws_size >= need;

    float*  mag = (float*)(ws);
    float2* tA  = (float2*)(ws + (size_t)4  * MB);
    float2* tB  = (float2*)(ws + (size_t)12 * MB);
    float*  dog = (float*)(ws + (size_t)12 * MB);
    float*  TV  = (float*)(ws + (size_t)20 * MB);
    float*  TH  = (float*)(ws + (size_t)40 * MB);
    size_t  tail = fast ? (size_t)60 * MB : (size_t)20 * MB;
    float*        partial = (float*)(ws + tail);
    unsigned int* maxbits = (unsigned int*)(ws + tail + NBLOCKS * sizeof(float));

    dim3 blk(256, 1, 1);
    dim3 sgrd(8, 256, 1);   // slab-aligned grid: blockIdx.x % 8 == slab == XCD

    k_sobel<<<sgrd, blk, 0, stream>>>(img, mag, tA, partial);
    k_reduce<<<1, 256, 0, stream>>>(partial, maxbits);

    float2* src = tA;
    float2* dst = tB;
    if (fast) {
        k_tanh<<<sgrd, blk, 0, stream>>>(mag, maxbits, TV, TH);
        for (int it = 0; it < 3; ++it) {
            k_etf_v<<<sgrd, blk, 0, stream>>>(src, dst, TV);
            { float2* t = src; src = dst; dst = t; }
            k_etf_h<<<sgrd, blk, 0, stream>>>(src, dst, TH);
            { float2* t = src; src = dst; dst = t; }
        }
    } else {
        dim3 grd(SY / 256, SX, BN);
        k_norm<<<NPIX / 256, 256, 0, stream>>>(mag, maxbits);
        for (int it = 0; it < 3; ++it) {
            k_etf<<<grd, blk, 0, stream>>>(src, dst, mag, 1);
            { float2* t = src; src = dst; dst = t; }
            k_etf<<<grd, blk, 0, stream>>>(src, dst, mag, 0);
            { float2* t = src; src = dst; dst = t; }
        }
    }
    float* dogbuf = (src == tA) ? dog : (float*)tA;

    DogW dw;
    {
        double tw = 0.0;
        for (int t = -3; t <= 3; ++t) {
            double g = gpdf((double)t, 1.0) - 0.99 * gpdf((double)t, 1.6);
            dw.g[t + 3] = (float)g;
            tw += g;
        }
        dw.tw = (float)tw;
    }
    k_dog<<<sgrd, blk, 0, stream>>>(img, src, dogbuf, dw);

    FdogW fw;
    {
        for (int s = 0; s <= 9; ++s) fw.g[s] = (float)gpdf((double)s, 3.0);
        double tw = 0.0;
        for (int s = 1; s <= 9; ++s) tw += gpdf((double)s, 3.0);
        for (int s = 0; s <= 9; ++s) tw += gpdf((double)s, 3.0);
        fw.tw = (float)tw;
    }
    k_fdog<<<sgrd, blk, 0, stream>>>(dogbuf, src, out, fw);
}